// Round 15
// baseline (2183.151 us; speedup 1.0000x reference)
//
#include <hip/hip_runtime.h>
#include <cstddef>

#define TSTEPS 128
#define BATCH  256
#define DIN    600
#define NR     6
#define KACT   4
#define DH     100
#define DK     64
#define DV     400
#define G3     300
#define LD1    512    // PRE1 row stride: [kx(64) | vx(400) | pad(48)]
#define LDG    1920   // GX row stride: [gi(1800) | pad(120)]
#define KB     8      // GEMM k-tile depth

// ---------- W1[600][512] = [Wk | Wv | 0] ----------
__global__ __launch_bounds__(256) void build_w1(const float* __restrict__ Wk,
                                                const float* __restrict__ Wv,
                                                float* __restrict__ W1) {
  int idx = blockIdx.x * 256 + threadIdx.x;
  if (idx >= DIN * LD1) return;
  int d = idx >> 9, c = idx & (LD1 - 1);
  float v = 0.f;
  if (c < DK)            v = Wk[d * DK + c];
  else if (c < DK + DV)  v = Wv[d * DV + (c - DK)];
  W1[idx] = v;
}

// ---------- WT[400][1920]: WT[v][n*300+j] = W_ih[n][v][j], zero pad ----------
__global__ __launch_bounds__(256) void build_wt(const float* __restrict__ Wih,
                                                float* __restrict__ WT) {
  int idx = blockIdx.x * 256 + threadIdx.x;
  if (idx >= DV * LDG) return;
  int v = idx / LDG, c = idx - v * LDG;
  float w = 0.f;
  if (c < NR * G3) { int n = c / G3, j = c - n * G3; w = Wih[(n * DV + v) * G3 + j]; }
  WT[idx] = w;
}

// ---------- fp32 GEMM (R14 verbatim: 128x128, 8x8, dbuf, B 12-stride swizzle, ----------
// ---------- grid.x = N-panels for A-tile L2 locality) ----------
__global__ __launch_bounds__(256) void sgemm_k(const float* __restrict__ A, int lda,
                                               const float* __restrict__ B, int ldb,
                                               float* __restrict__ C, int ldc, int K) {
  __shared__ float As[2][KB][132];   // 8.4 KB
  __shared__ float Bs[2][KB][192];   // 12.3 KB
  const int tid = threadIdx.x;
  const int tx = tid & 15, ty = tid >> 4;
  const size_t m0 = (size_t)blockIdx.y * 128, n0 = (size_t)blockIdx.x * 128;
  const int arow = tid >> 1, akq = (tid & 1) * 4;
  const int brow = tid >> 5, bcol = (tid & 31) * 4;
  const int bphys = bcol + ((bcol >> 3) << 2);
  const float* Ap = A + (m0 + arow) * (size_t)lda + akq;
  const float* Bp = B + (size_t)brow * ldb + n0 + bcol;

  float acc[8][8];
#pragma unroll
  for (int i = 0; i < 8; ++i)
#pragma unroll
    for (int j = 0; j < 8; ++j) acc[i][j] = 0.f;

  const int NT = K / KB;
  float4 av = *(const float4*)(Ap);
  float4 bv = *(const float4*)(Bp);
  As[0][akq + 0][arow] = av.x;
  As[0][akq + 1][arow] = av.y;
  As[0][akq + 2][arow] = av.z;
  As[0][akq + 3][arow] = av.w;
  *(float4*)&Bs[0][brow][bphys] = bv;
  __syncthreads();

  int cur = 0;
  for (int it = 0; it < NT; ++it) {
    if (it + 1 < NT) {
      av = *(const float4*)(Ap + (it + 1) * KB);
      bv = *(const float4*)(Bp + (size_t)(it + 1) * KB * ldb);
    }
#pragma unroll
    for (int k = 0; k < KB; ++k) {
      float a[8], b[8];
      *(float4*)&a[0] = *(const float4*)&As[cur][k][ty * 8];
      *(float4*)&a[4] = *(const float4*)&As[cur][k][ty * 8 + 4];
      *(float4*)&b[0] = *(const float4*)&Bs[cur][k][tx * 12];
      *(float4*)&b[4] = *(const float4*)&Bs[cur][k][tx * 12 + 4];
#pragma unroll
      for (int i = 0; i < 8; ++i)
#pragma unroll
        for (int j = 0; j < 8; ++j) acc[i][j] += a[i] * b[j];
    }
    if (it + 1 < NT) {
      const int nxt = cur ^ 1;
      As[nxt][akq + 0][arow] = av.x;
      As[nxt][akq + 1][arow] = av.y;
      As[nxt][akq + 2][arow] = av.z;
      As[nxt][akq + 3][arow] = av.w;
      *(float4*)&Bs[nxt][brow][bphys] = bv;
      __syncthreads();
      cur = nxt;
    }
  }

  float* Cp = C + (m0 + (size_t)ty * 8) * ldc + n0 + tx * 8;
#pragma unroll
  for (int i = 0; i < 8; ++i) {
    float4 v0 = make_float4(acc[i][0], acc[i][1], acc[i][2], acc[i][3]);
    float4 v1 = make_float4(acc[i][4], acc[i][5], acc[i][6], acc[i][7]);
    *(float4*)(Cp + (size_t)i * ldc)     = v0;
    *(float4*)(Cp + (size_t)i * ldc + 4) = v1;
  }
}

// ---------- RIMs scan: 192 blocks x 512 threads, intra-step wave split ----------
// Waves 0-1 (lanes 0-49 each): gh + GRU with COLUMN-PAIR weight packing —
//   thread (cp, batch-half) computes cols {2cp, 2cp+1} x 3 gates x 4 batches.
//   wpbuf quad = (w[2c][2h], w[2c+1][2h], w[2c][2h+1], w[2c+1][2h+1]) so one
//   b128 feeds 2 cols x 2 hh: per 4-hh iter, 6 w + 4 h reads for 96 FMAs
//   (vs 14 reads in R14) -> gh LDS instr/step 700 -> 500. Accumulation per
//   output stays single-thread ascending-hh -> bit-identical to R7-R14.
// Waves 4-7: q + score + publish (R7 verbatim).
// Cross-rim exchange: relaxed u64 atomics (epoch<<32)|p_bits, parity slots.
__global__ __launch_bounds__(512) void rim_scan(
    const float* __restrict__ PRE1, const float* __restrict__ GX,
    const float* __restrict__ Wq,   const float* __restrict__ Whh,
    const float* __restrict__ bih,  const float* __restrict__ bhh,
    float* __restrict__ out, float* __restrict__ hstate,
    unsigned long long* __restrict__ pbuf,
    int t0, int tc, int first) {
  __shared__ __align__(16) float wpbuf[50 * 3 * 50 * 4]; // 120.0 KB paired-col quads
  __shared__ __align__(16) float wqbuf[DK * DH];         //  25.6 KB Wq[n] [k][hh]
  __shared__ __align__(16) float hbuf[8 * DH];           //   3.2 KB h [b][hh]
  __shared__ float pl[8][NR];

  const int tid = threadIdx.x;
  const int g = blockIdx.x & 31;   // batch group
  const int n = blockIdx.x >> 5;   // rim

  // ---- stage wpbuf: quad (ph,g,cp) = {w[2cp][2ph], w[2cp+1][2ph],
  //                                     w[2cp][2ph+1], w[2cp+1][2ph+1]} ----
  {
    const float* wsrc = Whh + (size_t)n * (DH * G3);       // [hh][col]
    for (int i = tid; i < 50 * 3 * 50; i += 512) {
      int ph = i / 150;
      int r  = i - ph * 150;
      int gg = r / 50;
      int cp = r - gg * 50;
      const float* base = wsrc + (2 * ph) * G3 + gg * 100 + 2 * cp;
      float4 q;
      q.x = base[0];
      q.y = base[1];
      q.z = base[G3];
      q.w = base[G3 + 1];
      *(float4*)&wpbuf[i * 4] = q;
    }
    const float* qsrc = Wq + (size_t)n * (DH * DK);        // [hh][k]
    for (int i = tid; i < DH * DK; i += 512) {
      int hh = i >> 6, k = i & 63;
      wqbuf[k * DH + hh] = qsrc[i];
    }
    if (first) {
      for (int i = tid; i < 8 * DH; i += 512) hbuf[i] = 0.f;
    } else {
      for (int i = tid; i < 8 * DH; i += 512) {
        int b = i / DH, hh = i - b * DH;
        hbuf[b * DH + hh] = hstate[((size_t)(g * 8 + b) * NR + n) * DH + hh];
      }
    }
  }
  __syncthreads();

  const bool isQ = tid >= 256;       // waves 4-7: q/score/publish
  const int wv = tid >> 6, lane = tid & 63;
  const bool ghA = (wv < 2) && (lane < 50);   // gh threads: 2 waves x 50 lanes
  const int bh = wv & 1;             // batch half (0: b0-3, 1: b4-7)
  const int cp = lane;               // column pair (cols 2cp, 2cp+1)
  const int bbase = bh * 4;
  const int kq = tid & 63;
  const int bp2 = (tid >> 6) & 3;    // (q waves) handles batches bp2, bp2+4

  // ---- biases -> registers, once ----
  float bi_[3][2], bh_[3][2];
  if (ghA) {
#pragma unroll
    for (int gg = 0; gg < 3; ++gg)
#pragma unroll
      for (int c = 0; c < 2; ++c) {
        bi_[gg][c] = bih[(size_t)n * G3 + gg * 100 + 2 * cp + c];
        bh_[gg][c] = bhh[(size_t)n * G3 + gg * 100 + 2 * cp + c];
      }
  }

  const float4* wp = (const float4*)wpbuf;
  const float4* wq4 = (const float4*)&wqbuf[kq * DH];
  const float4* hq4[4] = {
    (const float4*)&hbuf[(bbase + 0) * DH],
    (const float4*)&hbuf[(bbase + 1) * DH],
    (const float4*)&hbuf[(bbase + 2) * DH],
    (const float4*)&hbuf[(bbase + 3) * DH]
  };
  const float4* hqA = (const float4*)&hbuf[bp2 * DH];
  const float4* hqB = (const float4*)&hbuf[(bp2 + 4) * DH];

  for (int tl = 0; tl < tc; ++tl) {
    const int t = t0 + tl;
    const int par = t & 1;

    float gx[4][3][2];
    float acc[4][3][2];

    if (isQ) {
      // ---- q = h @ Wq + butterfly score + publish (R7 verbatim) ----
      float kx0 = PRE1[((size_t)tl * BATCH + g * 8 + bp2) * LD1 + kq];
      float kx1 = PRE1[((size_t)tl * BATCH + g * 8 + bp2 + 4) * LD1 + kq];
      float a0 = 0.f, a1 = 0.f;
#pragma unroll 5
      for (int q4 = 0; q4 < 25; ++q4) {
        float4 w = wq4[q4];
        float4 v0 = hqA[q4];
        float4 v1 = hqB[q4];
        a0 += v0.x * w.x; a0 += v0.y * w.y; a0 += v0.z * w.z; a0 += v0.w * w.w;
        a1 += v1.x * w.x; a1 += v1.y * w.y; a1 += v1.z * w.z; a1 += v1.w * w.w;
      }
      float s0 = a0 * kx0, s1 = a1 * kx1;
#pragma unroll
      for (int off = 1; off < 64; off <<= 1) {
        s0 += __shfl_xor(s0, off);
        s1 += __shfl_xor(s1, off);
      }
      if (kq == 0) {
        float sa = s0 * 0.125f;
        float ma = sa > 0.f ? sa : 0.f;
        float pa = expf(sa - ma) / (expf(sa - ma) + expf(-ma));
        float sb = s1 * 0.125f;
        float mb = sb > 0.f ? sb : 0.f;
        float pb = expf(sb - mb) / (expf(sb - mb) + expf(-mb));
        unsigned long long tag = ((unsigned long long)(unsigned)(t + 1)) << 32;
        __hip_atomic_store(&pbuf[(((size_t)par * 32 + g) * NR + n) * 8 + bp2],
                           tag | __float_as_uint(pa),
                           __ATOMIC_RELAXED, __HIP_MEMORY_SCOPE_AGENT);
        __hip_atomic_store(&pbuf[(((size_t)par * 32 + g) * NR + n) * 8 + bp2 + 4],
                           tag | __float_as_uint(pb),
                           __ATOMIC_RELAXED, __HIP_MEMORY_SCOPE_AGENT);
      }
    } else if (ghA) {
      // ---- gx prefetch (float2 per gate per batch) ----
#pragma unroll
      for (int b = 0; b < 4; ++b) {
        const float* gr = GX + ((size_t)tl * BATCH + g * 8 + bbase + b) * LDG + n * G3;
#pragma unroll
        for (int gg = 0; gg < 3; ++gg) {
          float2 v = *(const float2*)(gr + gg * 100 + 2 * cp);
          gx[b][gg][0] = v.x; gx[b][gg][1] = v.y;
        }
      }
      // ---- gh = h @ Whh, paired-column quads; ascending-hh per accumulator ----
#pragma unroll
      for (int b = 0; b < 4; ++b)
#pragma unroll
        for (int gg = 0; gg < 3; ++gg) { acc[b][gg][0] = 0.f; acc[b][gg][1] = 0.f; }
#pragma unroll 5
      for (int pp = 0; pp < 25; ++pp) {
        float4 wA0 = wp[(6 * pp + 0) * 50 + cp];
        float4 wA1 = wp[(6 * pp + 1) * 50 + cp];
        float4 wA2 = wp[(6 * pp + 2) * 50 + cp];
        float4 wB0 = wp[(6 * pp + 3) * 50 + cp];
        float4 wB1 = wp[(6 * pp + 4) * 50 + cp];
        float4 wB2 = wp[(6 * pp + 5) * 50 + cp];
#pragma unroll
        for (int b = 0; b < 4; ++b) {
          float4 h = hq4[b][pp];
          acc[b][0][0] += h.x*wA0.x; acc[b][0][0] += h.y*wA0.z; acc[b][0][0] += h.z*wB0.x; acc[b][0][0] += h.w*wB0.z;
          acc[b][0][1] += h.x*wA0.y; acc[b][0][1] += h.y*wA0.w; acc[b][0][1] += h.z*wB0.y; acc[b][0][1] += h.w*wB0.w;
          acc[b][1][0] += h.x*wA1.x; acc[b][1][0] += h.y*wA1.z; acc[b][1][0] += h.z*wB1.x; acc[b][1][0] += h.w*wB1.z;
          acc[b][1][1] += h.x*wA1.y; acc[b][1][1] += h.y*wA1.w; acc[b][1][1] += h.z*wB1.y; acc[b][1][1] += h.w*wB1.w;
          acc[b][2][0] += h.x*wA2.x; acc[b][2][0] += h.y*wA2.z; acc[b][2][0] += h.z*wB2.x; acc[b][2][0] += h.w*wB2.z;
          acc[b][2][1] += h.x*wA2.y; acc[b][2][1] += h.y*wA2.w; acc[b][2][1] += h.z*wB2.y; acc[b][2][1] += h.w*wB2.w;
        }
      }
    }

    // ---- lanes 0-47 of wave 0: gather 6 rims' p via epoch-tagged u64 spin ----
    if (tid < 48) {
      int b = tid & 7, r = tid >> 3;
      const unsigned want = (unsigned)(t + 1);
      unsigned long long v;
      for (;;) {
        v = __hip_atomic_load(&pbuf[(((size_t)par * 32 + g) * NR + r) * 8 + b],
                              __ATOMIC_RELAXED, __HIP_MEMORY_SCOPE_AGENT);
        if ((unsigned)(v >> 32) == want) break;
        __builtin_amdgcn_s_sleep(1);
      }
      pl[b][r] = __uint_as_float((unsigned)v);
    }
    __syncthreads();   // A: pl visible; all hbuf reads complete

    // ---- top-k mask + GRU pointwise + state update (formulas identical) ----
    if (ghA) {
#pragma unroll
      for (int b = 0; b < 4; ++b) {
        const int bb = bbase + b;
        float p = pl[bb][n];
        int c = 0;
#pragma unroll
        for (int r = 0; r < NR; ++r) {
          float q = pl[bb][r];
          if (q > p || (q == p && r < n)) ++c;
        }
        float m = (c < KACT) ? 1.f : 0.f;
        float hn2[2];
#pragma unroll
        for (int cc = 0; cc < 2; ++cc) {
          float grv = acc[b][0][cc] + bh_[0][cc];
          float gzv = acc[b][1][cc] + bh_[1][cc];
          float gnv = acc[b][2][cc] + bh_[2][cc];
          float ir  = p * gx[b][0][cc] + bi_[0][cc];
          float iz  = p * gx[b][1][cc] + bi_[1][cc];
          float inn = p * gx[b][2][cc] + bi_[2][cc];
          float rr = 1.f / (1.f + expf(-(ir + grv)));
          float zz = 1.f / (1.f + expf(-(iz + gzv)));
          float nn = tanhf(inn + rr * gnv);
          float hprev = hbuf[bb * DH + 2 * cp + cc];
          float hnew = (1.f - zz) * nn + zz * hprev;
          hn2[cc] = hnew;
        }
        float2 ov = make_float2(m * hn2[0], m * hn2[1]);
        *(float2*)&out[(((size_t)t * BATCH + g * 8 + bb) * NR + n) * DH + 2 * cp] = ov;
        if (m > 0.f) {
          *(float2*)&hbuf[bb * DH + 2 * cp] = make_float2(hn2[0], hn2[1]);
        }
      }
    }
    __syncthreads();   // B: h(t) visible to next step's q and gh
  }

  for (int i = tid; i < 8 * DH; i += 512) {
    int b = i / DH, hh = i - b * DH;
    hstate[((size_t)(g * 8 + b) * NR + n) * DH + hh] = hbuf[b * DH + hh];
  }
}

extern "C" void kernel_launch(void* const* d_in, const int* in_sizes, int n_in,
                              void* d_out, int out_size, void* d_ws, size_t ws_size,
                              hipStream_t stream) {
  const float* x   = (const float*)d_in[0];
  const float* Wq  = (const float*)d_in[1];
  const float* Wk  = (const float*)d_in[2];
  const float* Wv  = (const float*)d_in[3];
  const float* Wih = (const float*)d_in[4];
  const float* Whh = (const float*)d_in[5];
  const float* bih = (const float*)d_in[6];
  const float* bhh = (const float*)d_in[7];
  float* out = (float*)d_out;
  char* ws = (char*)d_ws;

  const size_t W1_BYTES   = (size_t)DIN * LD1 * 4;     // 1,228,800
  const size_t WT_BYTES   = (size_t)DV * LDG * 4;      // 3,072,000
  const size_t H_BYTES    = (size_t)BATCH * 600 * 4;   //   614,400
  const size_t PBUF_BYTES = 2 * 32 * NR * 8 * 8;       //    24,576 (u64)
  const size_t FIXED = W1_BYTES + WT_BYTES + H_BYTES + PBUF_BYTES;
  const size_t PER_STEP = (size_t)BATCH * (LD1 + LDG) * 4;  // 2,490,368

  float* W1     = (float*)ws;
  float* WT     = (float*)(ws + W1_BYTES);
  float* hstate = (float*)(ws + W1_BYTES + WT_BYTES);
  unsigned long long* pbuf =
      (unsigned long long*)(ws + W1_BYTES + WT_BYTES + H_BYTES);

  long long avail = (long long)ws_size - (long long)FIXED;
  int TC = 1;
  if (avail > 0) {
    long long t = avail / (long long)PER_STEP;
    TC = (int)(t < 1 ? 1 : (t > TSTEPS ? TSTEPS : t));
  }
  float* PRE1 = (float*)(ws + FIXED);
  float* GXb  = (float*)(ws + FIXED + (size_t)TC * BATCH * LD1 * 4);

  build_w1<<<(DIN * LD1) / 256, 256, 0, stream>>>(Wk, Wv, W1);
  build_wt<<<(DV * LDG) / 256, 256, 0, stream>>>(Wih, WT);

  for (int t0 = 0; t0 < TSTEPS; ) {
    int tc = TSTEPS - t0 < TC ? TSTEPS - t0 : TC;
    // grid.x = N-panels (fast) so consecutive blocks share an A-tile (L2-hot)
    dim3 g1(LD1 / 128, tc * 2);
    sgemm_k<<<g1, 256, 0, stream>>>(x + (size_t)t0 * BATCH * DIN, DIN, W1, LD1, PRE1, LD1, DIN);
    dim3 g2(LDG / 128, tc * 2);
    sgemm_k<<<g2, 256, 0, stream>>>(PRE1 + DK, LD1, WT, LDG, GXb, LDG, DV);
    rim_scan<<<32 * NR, 512, 0, stream>>>(PRE1, GXb, Wq, Whh, bih, bhh, out, hstate,
                                          pbuf, t0, tc, t0 == 0 ? 1 : 0);
    t0 += tc;
  }
}

// Round 16
// 1886.736 us; speedup vs baseline: 1.1571x; 1.1571x over previous
//
#include <hip/hip_runtime.h>
#include <cstddef>

#define TSTEPS 128
#define BATCH  256
#define DIN    600
#define NR     6
#define KACT   4
#define DH     100
#define DK     64
#define DV     400
#define G3     300
#define LD1    512    // PRE1 row stride: [kx(64) | vx(400) | pad(48)]
#define LDG    1920   // GX row stride: [gi(1800) | pad(120)]
#define KB     8      // GEMM k-tile depth

// ---------- W1[600][512] = [Wk | Wv | 0] ----------
__global__ __launch_bounds__(256) void build_w1(const float* __restrict__ Wk,
                                                const float* __restrict__ Wv,
                                                float* __restrict__ W1) {
  int idx = blockIdx.x * 256 + threadIdx.x;
  if (idx >= DIN * LD1) return;
  int d = idx >> 9, c = idx & (LD1 - 1);
  float v = 0.f;
  if (c < DK)            v = Wk[d * DK + c];
  else if (c < DK + DV)  v = Wv[d * DV + (c - DK)];
  W1[idx] = v;
}

// ---------- WT[400][1920]: WT[v][n*300+j] = W_ih[n][v][j], zero pad ----------
__global__ __launch_bounds__(256) void build_wt(const float* __restrict__ Wih,
                                                float* __restrict__ WT) {
  int idx = blockIdx.x * 256 + threadIdx.x;
  if (idx >= DV * LDG) return;
  int v = idx / LDG, c = idx - v * LDG;
  float w = 0.f;
  if (c < NR * G3) { int n = c / G3, j = c - n * G3; w = Wih[(n * DV + v) * G3 + j]; }
  WT[idx] = w;
}

// ---------- fp32 GEMM (R14 verbatim: 128x128, 8x8, dbuf, B 12-stride swizzle, ----------
// ---------- grid.x = N-panels for A-tile L2 locality) ----------
__global__ __launch_bounds__(256) void sgemm_k(const float* __restrict__ A, int lda,
                                               const float* __restrict__ B, int ldb,
                                               float* __restrict__ C, int ldc, int K) {
  __shared__ float As[2][KB][132];   // 8.4 KB
  __shared__ float Bs[2][KB][192];   // 12.3 KB
  const int tid = threadIdx.x;
  const int tx = tid & 15, ty = tid >> 4;
  const size_t m0 = (size_t)blockIdx.y * 128, n0 = (size_t)blockIdx.x * 128;
  const int arow = tid >> 1, akq = (tid & 1) * 4;
  const int brow = tid >> 5, bcol = (tid & 31) * 4;
  const int bphys = bcol + ((bcol >> 3) << 2);
  const float* Ap = A + (m0 + arow) * (size_t)lda + akq;
  const float* Bp = B + (size_t)brow * ldb + n0 + bcol;

  float acc[8][8];
#pragma unroll
  for (int i = 0; i < 8; ++i)
#pragma unroll
    for (int j = 0; j < 8; ++j) acc[i][j] = 0.f;

  const int NT = K / KB;
  float4 av = *(const float4*)(Ap);
  float4 bv = *(const float4*)(Bp);
  As[0][akq + 0][arow] = av.x;
  As[0][akq + 1][arow] = av.y;
  As[0][akq + 2][arow] = av.z;
  As[0][akq + 3][arow] = av.w;
  *(float4*)&Bs[0][brow][bphys] = bv;
  __syncthreads();

  int cur = 0;
  for (int it = 0; it < NT; ++it) {
    if (it + 1 < NT) {
      av = *(const float4*)(Ap + (it + 1) * KB);
      bv = *(const float4*)(Bp + (size_t)(it + 1) * KB * ldb);
    }
#pragma unroll
    for (int k = 0; k < KB; ++k) {
      float a[8], b[8];
      *(float4*)&a[0] = *(const float4*)&As[cur][k][ty * 8];
      *(float4*)&a[4] = *(const float4*)&As[cur][k][ty * 8 + 4];
      *(float4*)&b[0] = *(const float4*)&Bs[cur][k][tx * 12];
      *(float4*)&b[4] = *(const float4*)&Bs[cur][k][tx * 12 + 4];
#pragma unroll
      for (int i = 0; i < 8; ++i)
#pragma unroll
        for (int j = 0; j < 8; ++j) acc[i][j] += a[i] * b[j];
    }
    if (it + 1 < NT) {
      const int nxt = cur ^ 1;
      As[nxt][akq + 0][arow] = av.x;
      As[nxt][akq + 1][arow] = av.y;
      As[nxt][akq + 2][arow] = av.z;
      As[nxt][akq + 3][arow] = av.w;
      *(float4*)&Bs[nxt][brow][bphys] = bv;
      __syncthreads();
      cur = nxt;
    }
  }

  float* Cp = C + (m0 + (size_t)ty * 8) * ldc + n0 + tx * 8;
#pragma unroll
  for (int i = 0; i < 8; ++i) {
    float4 v0 = make_float4(acc[i][0], acc[i][1], acc[i][2], acc[i][3]);
    float4 v1 = make_float4(acc[i][4], acc[i][5], acc[i][6], acc[i][7]);
    *(float4*)(Cp + (size_t)i * ldc)     = v0;
    *(float4*)(Cp + (size_t)i * ldc + 4) = v1;
  }
}

// ---------- RIMs scan: 192 blocks x 512 threads, intra-step wave split ----------
// (R14 structure.)  Waves 0-3: gh + GRU.  Waves 4-7: q + score + publish,
// AND (new vs R14) lanes 0-47 of wave 4 do the p-gather spin — q waves are
// idle after publishing, so the cross-rim exchange latency is absorbed off
// the gh critical path (wave 0 previously spun serially after its gh).
// Cross-rim exchange: relaxed u64 atomics (epoch<<32)|p_bits, parity slots.
// All arithmetic identical to R7-R14 -> bit-identical output.
__global__ __launch_bounds__(512) void rim_scan(
    const float* __restrict__ PRE1, const float* __restrict__ GX,
    const float* __restrict__ Wq,   const float* __restrict__ Whh,
    const float* __restrict__ bih,  const float* __restrict__ bhh,
    float* __restrict__ out, float* __restrict__ hstate,
    unsigned long long* __restrict__ pbuf,
    int t0, int tc, int first) {
  __shared__ __align__(16) float wbuf[G3 * DH];   // 120.0 KB  Whh[n] transposed [col][hh]
  __shared__ __align__(16) float wqbuf[DK * DH];  //  25.6 KB  Wq[n] transposed [k][hh]
  __shared__ __align__(16) float hbuf[8 * DH];    //   3.2 KB  h [b][hh]
  __shared__ float pl[8][NR];

  const int tid = threadIdx.x;
  const int g = blockIdx.x & 31;   // batch group
  const int n = blockIdx.x >> 5;   // rim

  {
    const float* wsrc = Whh + (size_t)n * (DH * G3);       // [hh][col]
    for (int i = tid; i < DH * G3; i += 512) {
      int hh = i / G3, c = i - hh * G3;
      wbuf[c * DH + hh] = wsrc[i];
    }
    const float* qsrc = Wq + (size_t)n * (DH * DK);        // [hh][k]
    for (int i = tid; i < DH * DK; i += 512) {
      int hh = i >> 6, k = i & 63;
      wqbuf[k * DH + hh] = qsrc[i];
    }
    if (first) {
      for (int i = tid; i < 8 * DH; i += 512) hbuf[i] = 0.f;
    } else {
      for (int i = tid; i < 8 * DH; i += 512) {
        int b = i / DH, hh = i - b * DH;
        hbuf[b * DH + hh] = hstate[((size_t)(g * 8 + b) * NR + n) * DH + hh];
      }
    }
  }
  __syncthreads();

  const bool isQ = tid >= 256;     // waves 4-7: q/score/publish
  const int ho = tid & 127;        // (gh waves) output hidden index, valid < 100
  const bool act_t = (!isQ) && (ho < DH);
  const int half = (tid >> 7) & 1;
  const int bbase = half * 4;
  const int kq = tid & 63;
  const int bp2 = (tid >> 6) & 3;  // (q waves) handles batches bp2, bp2+4

  float bi0 = 0.f, bi1 = 0.f, bi2 = 0.f, bh0 = 0.f, bh1 = 0.f, bh2 = 0.f;
  if (act_t) {
    const float* bi = bih + (size_t)n * G3 + ho;
    const float* bh = bhh + (size_t)n * G3 + ho;
    bi0 = bi[0]; bi1 = bi[DH]; bi2 = bi[2 * DH];
    bh0 = bh[0]; bh1 = bh[DH]; bh2 = bh[2 * DH];
  }

  const float4* wr = (const float4*)&wbuf[ho * DH];
  const float4* wz = (const float4*)&wbuf[(ho + 100) * DH];
  const float4* wn = (const float4*)&wbuf[(ho + 200) * DH];
  const float4* wq4 = (const float4*)&wqbuf[kq * DH];
  const float4* h40 = (const float4*)&hbuf[(bbase + 0) * DH];
  const float4* h41 = (const float4*)&hbuf[(bbase + 1) * DH];
  const float4* h42 = (const float4*)&hbuf[(bbase + 2) * DH];
  const float4* h43 = (const float4*)&hbuf[(bbase + 3) * DH];
  const float4* hqA = (const float4*)&hbuf[bp2 * DH];
  const float4* hqB = (const float4*)&hbuf[(bp2 + 4) * DH];

  for (int tl = 0; tl < tc; ++tl) {
    const int t = t0 + tl;
    const int par = t & 1;

    float gx[4][3];
    float acc[4][3];

    if (isQ) {
      float kx0 = PRE1[((size_t)tl * BATCH + g * 8 + bp2) * LD1 + kq];
      float kx1 = PRE1[((size_t)tl * BATCH + g * 8 + bp2 + 4) * LD1 + kq];
      float a0 = 0.f, a1 = 0.f;
#pragma unroll 5
      for (int q4 = 0; q4 < 25; ++q4) {
        float4 w = wq4[q4];
        float4 v0 = hqA[q4];
        float4 v1 = hqB[q4];
        a0 += v0.x * w.x; a0 += v0.y * w.y; a0 += v0.z * w.z; a0 += v0.w * w.w;
        a1 += v1.x * w.x; a1 += v1.y * w.y; a1 += v1.z * w.z; a1 += v1.w * w.w;
      }
      float s0 = a0 * kx0, s1 = a1 * kx1;
#pragma unroll
      for (int off = 1; off < 64; off <<= 1) {
        s0 += __shfl_xor(s0, off);
        s1 += __shfl_xor(s1, off);
      }
      if (kq == 0) {
        float sa = s0 * 0.125f;
        float ma = sa > 0.f ? sa : 0.f;
        float pa = expf(sa - ma) / (expf(sa - ma) + expf(-ma));
        float sb = s1 * 0.125f;
        float mb = sb > 0.f ? sb : 0.f;
        float pb = expf(sb - mb) / (expf(sb - mb) + expf(-mb));
        unsigned long long tag = ((unsigned long long)(unsigned)(t + 1)) << 32;
        __hip_atomic_store(&pbuf[(((size_t)par * 32 + g) * NR + n) * 8 + bp2],
                           tag | __float_as_uint(pa),
                           __ATOMIC_RELAXED, __HIP_MEMORY_SCOPE_AGENT);
        __hip_atomic_store(&pbuf[(((size_t)par * 32 + g) * NR + n) * 8 + bp2 + 4],
                           tag | __float_as_uint(pb),
                           __ATOMIC_RELAXED, __HIP_MEMORY_SCOPE_AGENT);
      }
      // ---- (new) lanes 0-47 of wave 4 gather all 6 rims' p while gh runs ----
      if (tid < 304) {
        int t2 = tid - 256;
        int b = t2 & 7, r = t2 >> 3;
        const unsigned want = (unsigned)(t + 1);
        unsigned long long v;
        for (;;) {
          v = __hip_atomic_load(&pbuf[(((size_t)par * 32 + g) * NR + r) * 8 + b],
                                __ATOMIC_RELAXED, __HIP_MEMORY_SCOPE_AGENT);
          if ((unsigned)(v >> 32) == want) break;
          __builtin_amdgcn_s_sleep(1);
        }
        pl[b][r] = __uint_as_float((unsigned)v);
      }
    } else if (act_t) {
#pragma unroll
      for (int b = 0; b < 4; ++b) {
        const float* gr = GX + ((size_t)tl * BATCH + g * 8 + bbase + b) * LDG + n * G3;
        gx[b][0] = gr[ho]; gx[b][1] = gr[ho + DH]; gx[b][2] = gr[ho + 2 * DH];
      }
#pragma unroll
      for (int b = 0; b < 4; ++b) { acc[b][0] = 0.f; acc[b][1] = 0.f; acc[b][2] = 0.f; }
#pragma unroll 5
      for (int q4 = 0; q4 < 25; ++q4) {
        float4 w0 = wr[q4], w1 = wz[q4], w2 = wn[q4];
        float4 v0 = h40[q4], v1 = h41[q4], v2 = h42[q4], v3 = h43[q4];
        acc[0][0] += v0.x*w0.x; acc[0][0] += v0.y*w0.y; acc[0][0] += v0.z*w0.z; acc[0][0] += v0.w*w0.w;
        acc[0][1] += v0.x*w1.x; acc[0][1] += v0.y*w1.y; acc[0][1] += v0.z*w1.z; acc[0][1] += v0.w*w1.w;
        acc[0][2] += v0.x*w2.x; acc[0][2] += v0.y*w2.y; acc[0][2] += v0.z*w2.z; acc[0][2] += v0.w*w2.w;
        acc[1][0] += v1.x*w0.x; acc[1][0] += v1.y*w0.y; acc[1][0] += v1.z*w0.z; acc[1][0] += v1.w*w0.w;
        acc[1][1] += v1.x*w1.x; acc[1][1] += v1.y*w1.y; acc[1][1] += v1.z*w1.z; acc[1][1] += v1.w*w1.w;
        acc[1][2] += v1.x*w2.x; acc[1][2] += v1.y*w2.y; acc[1][2] += v1.z*w2.z; acc[1][2] += v1.w*w2.w;
        acc[2][0] += v2.x*w0.x; acc[2][0] += v2.y*w0.y; acc[2][0] += v2.z*w0.z; acc[2][0] += v2.w*w0.w;
        acc[2][1] += v2.x*w1.x; acc[2][1] += v2.y*w1.y; acc[2][1] += v2.z*w1.z; acc[2][1] += v2.w*w1.w;
        acc[2][2] += v2.x*w2.x; acc[2][2] += v2.y*w2.y; acc[2][2] += v2.z*w2.z; acc[2][2] += v2.w*w2.w;
        acc[3][0] += v3.x*w0.x; acc[3][0] += v3.y*w0.y; acc[3][0] += v3.z*w0.z; acc[3][0] += v3.w*w0.w;
        acc[3][1] += v3.x*w1.x; acc[3][1] += v3.y*w1.y; acc[3][1] += v3.z*w1.z; acc[3][1] += v3.w*w1.w;
        acc[3][2] += v3.x*w2.x; acc[3][2] += v3.y*w2.y; acc[3][2] += v3.z*w2.z; acc[3][2] += v3.w*w2.w;
      }
    }

    __syncthreads();   // A: pl visible; all hbuf reads complete

    if (act_t) {
#pragma unroll
      for (int b = 0; b < 4; ++b) {
        const int bb = bbase + b;
        float p = pl[bb][n];
        int c = 0;
#pragma unroll
        for (int r = 0; r < NR; ++r) {
          float q = pl[bb][r];
          if (q > p || (q == p && r < n)) ++c;
        }
        float m = (c < KACT) ? 1.f : 0.f;
        float grv = acc[b][0] + bh0;
        float gzv = acc[b][1] + bh1;
        float gnv = acc[b][2] + bh2;
        float ir  = p * gx[b][0] + bi0;
        float iz  = p * gx[b][1] + bi1;
        float inn = p * gx[b][2] + bi2;
        float rr = 1.f / (1.f + expf(-(ir + grv)));
        float zz = 1.f / (1.f + expf(-(iz + gzv)));
        float nn = tanhf(inn + rr * gnv);
        float hprev = hbuf[bb * DH + ho];
        float hnew = (1.f - zz) * nn + zz * hprev;
        out[(((size_t)t * BATCH + g * 8 + bb) * NR + n) * DH + ho] = m * hnew;
        hbuf[bb * DH + ho] = (m > 0.f) ? hnew : hprev;
      }
    }
    __syncthreads();   // B: h(t) visible to next step's q and gh
  }

  for (int i = tid; i < 8 * DH; i += 512) {
    int b = i / DH, hh = i - b * DH;
    hstate[((size_t)(g * 8 + b) * NR + n) * DH + hh] = hbuf[b * DH + hh];
  }
}

extern "C" void kernel_launch(void* const* d_in, const int* in_sizes, int n_in,
                              void* d_out, int out_size, void* d_ws, size_t ws_size,
                              hipStream_t stream) {
  const float* x   = (const float*)d_in[0];
  const float* Wq  = (const float*)d_in[1];
  const float* Wk  = (const float*)d_in[2];
  const float* Wv  = (const float*)d_in[3];
  const float* Wih = (const float*)d_in[4];
  const float* Whh = (const float*)d_in[5];
  const float* bih = (const float*)d_in[6];
  const float* bhh = (const float*)d_in[7];
  float* out = (float*)d_out;
  char* ws = (char*)d_ws;

  const size_t W1_BYTES   = (size_t)DIN * LD1 * 4;     // 1,228,800
  const size_t WT_BYTES   = (size_t)DV * LDG * 4;      // 3,072,000
  const size_t H_BYTES    = (size_t)BATCH * 600 * 4;   //   614,400
  const size_t PBUF_BYTES = 2 * 32 * NR * 8 * 8;       //    24,576 (u64)
  const size_t FIXED = W1_BYTES + WT_BYTES + H_BYTES + PBUF_BYTES;
  const size_t PER_STEP = (size_t)BATCH * (LD1 + LDG) * 4;  // 2,490,368

  float* W1     = (float*)ws;
  float* WT     = (float*)(ws + W1_BYTES);
  float* hstate = (float*)(ws + W1_BYTES + WT_BYTES);
  unsigned long long* pbuf =
      (unsigned long long*)(ws + W1_BYTES + WT_BYTES + H_BYTES);

  long long avail = (long long)ws_size - (long long)FIXED;
  int TC = 1;
  if (avail > 0) {
    long long t = avail / (long long)PER_STEP;
    TC = (int)(t < 1 ? 1 : (t > TSTEPS ? TSTEPS : t));
  }
  float* PRE1 = (float*)(ws + FIXED);
  float* GXb  = (float*)(ws + FIXED + (size_t)TC * BATCH * LD1 * 4);

  build_w1<<<(DIN * LD1) / 256, 256, 0, stream>>>(Wk, Wv, W1);
  build_wt<<<(DV * LDG) / 256, 256, 0, stream>>>(Wih, WT);

  for (int t0 = 0; t0 < TSTEPS; ) {
    int tc = TSTEPS - t0 < TC ? TSTEPS - t0 : TC;
    // grid.x = N-panels (fast) so consecutive blocks share an A-tile (L2-hot)
    dim3 g1(LD1 / 128, tc * 2);
    sgemm_k<<<g1, 256, 0, stream>>>(x + (size_t)t0 * BATCH * DIN, DIN, W1, LD1, PRE1, LD1, DIN);
    dim3 g2(LDG / 128, tc * 2);
    sgemm_k<<<g2, 256, 0, stream>>>(PRE1 + DK, LD1, WT, LDG, GXb, LDG, DV);
    rim_scan<<<32 * NR, 512, 0, stream>>>(PRE1, GXb, Wq, Whh, bih, bhh, out, hstate,
                                          pbuf, t0, tc, t0 == 0 ? 1 : 0);
    t0 += tc;
  }
}